// Round 13
// baseline (41.183 us; speedup 1.0000x reference)
//
#include <hip/hip_runtime.h>
#include <hip/hip_bf16.h>

// Problem constants
#define B_    64
#define T_    500
#define DIN   1024
#define DOUT  128
#define EPSV  1e-8f
#define BM    64           // t-rows per block tile
#define BK    32           // k per LDS stage
#define NKC   4            // k-chunks (exact: weighting is linear in h)
#define KCL   (DIN / NKC)  // 256
#define NKT   (KCL / BK)   // 8 K-steps per block
#define TILES 8            // ceil(500/64)
#define NGEMM (B_ * TILES * NKC)   // 2048 blocks -> 4/CU x 256 CU x 2 rounds
#define NPREP 32

typedef __attribute__((ext_vector_type(8))) short bf16x8;  // MFMA A/B frag
typedef __attribute__((ext_vector_type(4))) float f32x4;   // MFMA C/D frag

// Workspace layout (byte offsets)
//   wT       : bf16 [DOUT][DIN]                @ 0        (262144 B)
//   normPart : f32  [NPREP][DOUT]              @ 262144   (16384 B)
//   part     : f32  [B_][TILES][NKC][DOUT]     @ 278528   (1048576 B)
#define OFF_NORM  262144
#define OFF_PART  278528

__device__ inline short f2bf(float f) {
    __hip_bfloat16 h = __float2bfloat16(f);
    return __builtin_bit_cast(short, h);
}

// Raw barrier: LDS-drain only; global loads ride across with counted vmcnt.
__device__ inline void block_sync_lds() {
    asm volatile("s_waitcnt lgkmcnt(0)" ::: "memory");
    __builtin_amdgcn_s_barrier();
    asm volatile("" ::: "memory");
}

// ---------------- prep: transpose/convert w + per-block norm partials ----------------
__global__ __launch_bounds__(512) void prep_kernel(
    const float* __restrict__ w, __hip_bfloat16* __restrict__ wT,
    float* __restrict__ normPart)
{
    const int tid = threadIdx.x;
    const int blk = blockIdx.x;
    const int t   = blk * 512 + tid;
    const int d   = t & 127;
    const int kq  = t >> 7;                 // global 8-k group, 0..127
    float v[8];
    float ss = 0.f;
#pragma unroll
    for (int m = 0; m < 8; ++m) {
        v[m] = w[(size_t)(kq * 8 + m) * DOUT + d];
        ss += v[m] * v[m];
    }
    bf16x8 o;
#pragma unroll
    for (int m = 0; m < 8; ++m) o[m] = f2bf(v[m]);
    *reinterpret_cast<bf16x8*>(wT + (size_t)d * DIN + kq * 8) = o;

    __shared__ float red[512];
    red[tid] = ss;
    __syncthreads();
    if (tid < 128)
        normPart[blk * DOUT + tid] = red[tid] + red[tid + 128] + red[tid + 256] + red[tid + 384];
}

// ---------------- main: small-block LDS GEMM, 4 blocks/CU ----------------
// 2048 blocks = 64 b x 8 t-tiles x 4 k-chunks; 256 threads = 4 waves (2 wr x 2 wc).
// Wave owns 32 rows x 64 cols over K=256. LDS double-buffered A[64][32] + B[128][32] bf16,
// slot-swizzle: 16B slot' = slot ^ (row&3) within the 64B row (write & read involution).
// Pipeline: step kt: issue loads(kt+2) -> compute LDS[kt&1] -> cvt+write(kt+1) -> raw barrier.
// BUGFIX vs R11: B staging second chunk is bg + KB + 8 (thread owns k sh*8..sh*8+15),
// was +16 (skewed k by 16 and read past wT at kc=3,kt=7).
__global__ __launch_bounds__(256, 4) void gemm_kernel(
    const float* __restrict__ x, const float* __restrict__ beta,
    const __hip_bfloat16* __restrict__ wT, float* __restrict__ partials)
{
    __shared__ __align__(16) char smem[2 * 12288];  // per buf: A @0 (4KB), B @4KB (8KB)
    __shared__ float red[2][DOUT];                  // cross-wave reduce (by wr)

    const int tid  = threadIdx.x;
    const int wid  = tid >> 6;
    const int lane = tid & 63;
    const int arow = lane & 15;
    const int kblk = lane >> 4;
    const int wr   = wid >> 1;   // 0..1 (row group of 32)
    const int wc   = wid & 1;    // 0..1 (col group of 64)

    const int wg   = blockIdx.x;
    const int kc   = wg & 3;
    const int tile = (wg >> 2) & 7;
    const int b    = wg >> 5;
    const int t0   = tile * BM;
    const int kbase = kc * KCL;

    // ---- staging geometry (loop-invariant) ----
    // A: thread owns (row = tid>>2, slot c4 = tid&3): 8 k-elems = 2 float4 global, 1 bf16x8 LDS
    const int srow = tid >> 2;
    const int c4   = tid & 3;
    int trow = t0 + srow; if (trow >= T_) trow = T_ - 1;   // clamp; weight=0 kills it
    const float* ag = x + ((size_t)b * T_ + trow) * DIN + kbase + c4 * 8;
    const int awoff = srow * 64 + ((c4 ^ (srow & 3)) << 4);
    // B: thread owns (col = tid>>1, logical slots sh, sh+1): k elems sh*8 .. sh*8+15
    const int bcol = tid >> 1;
    const int sh   = (tid & 1) * 2;
    const __hip_bfloat16* bg = wT + (size_t)bcol * DIN + kbase + sh * 8;
    const int bwoff0 = bcol * 64 + (((sh)     ^ (bcol & 3)) << 4);
    const int bwoff1 = bcol * 64 + (((sh + 1) ^ (bcol & 3)) << 4);

    // fragment read offsets (slot = kblk, swizzled), loop-invariant
    int aro[2], bro[4];
#pragma unroll
    for (int fm = 0; fm < 2; ++fm) {
        int row = wr * 32 + fm * 16 + arow;
        aro[fm] = row * 64 + ((kblk ^ (row & 3)) << 4);
    }
#pragma unroll
    for (int fn = 0; fn < 4; ++fn) {
        int col = wc * 64 + fn * 16 + arow;
        bro[fn] = col * 64 + ((kblk ^ (col & 3)) << 4);
    }

    f32x4 acc[2][4] = {};

    // ---- register-queued pipeline (static names; rule #20) ----
#define DECL_SET(S) float4 S##a0, S##a1; bf16x8 S##b0, S##b1;
#define LOAD_SET(S, KB) \
    S##a0 = *reinterpret_cast<const float4*>(ag + (KB));      \
    S##a1 = *reinterpret_cast<const float4*>(ag + (KB) + 4);  \
    S##b0 = *reinterpret_cast<const bf16x8*>(bg + (KB));      \
    S##b1 = *reinterpret_cast<const bf16x8*>(bg + (KB) + 8);
#define WRITE_SET(S, AB, BB) { \
    bf16x8 ha; \
    ha[0]=f2bf(S##a0.x); ha[1]=f2bf(S##a0.y); ha[2]=f2bf(S##a0.z); ha[3]=f2bf(S##a0.w); \
    ha[4]=f2bf(S##a1.x); ha[5]=f2bf(S##a1.y); ha[6]=f2bf(S##a1.z); ha[7]=f2bf(S##a1.w); \
    *reinterpret_cast<bf16x8*>((AB) + awoff)  = ha;      \
    *reinterpret_cast<bf16x8*>((BB) + bwoff0) = S##b0;   \
    *reinterpret_cast<bf16x8*>((BB) + bwoff1) = S##b1; }
#define COMPUTE(AB, BB) { \
    bf16x8 af0 = *reinterpret_cast<const bf16x8*>((AB) + aro[0]); \
    bf16x8 af1 = *reinterpret_cast<const bf16x8*>((AB) + aro[1]); \
    _Pragma("unroll") \
    for (int fn = 0; fn < 4; ++fn) { \
        bf16x8 bf = *reinterpret_cast<const bf16x8*>((BB) + bro[fn]); \
        acc[0][fn] = __builtin_amdgcn_mfma_f32_16x16x32_bf16(af0, bf, acc[0][fn], 0, 0, 0); \
        acc[1][fn] = __builtin_amdgcn_mfma_f32_16x16x32_bf16(af1, bf, acc[1][fn], 0, 0, 0); \
    } }

    DECL_SET(qe_) DECL_SET(qo_)

    // ---- prologue: load kt=0,1; write kt=0 -> LDS0 ----
    LOAD_SET(qe_, 0)
    LOAD_SET(qo_, BK)
    WRITE_SET(qe_, smem, smem + 4096)
    block_sync_lds();

    // ---- main loop, fully unrolled ----
#pragma unroll
    for (int kt = 0; kt < NKT; ++kt) {
        char* Acur = smem + (kt & 1) * 12288;
        char* Bcur = Acur + 4096;
        char* Anxt = smem + ((kt + 1) & 1) * 12288;
        char* Bnxt = Anxt + 4096;

        if (kt + 2 < NKT) {
            if (kt & 1) { LOAD_SET(qo_, (kt + 2) * BK) }
            else        { LOAD_SET(qe_, (kt + 2) * BK) }
        }

        COMPUTE(Acur, Bcur)

        if (kt + 1 < NKT) {
            if (kt & 1) { WRITE_SET(qe_, Anxt, Bnxt) }
            else        { WRITE_SET(qo_, Anxt, Bnxt) }
            block_sync_lds();
        }
    }
#undef DECL_SET
#undef LOAD_SET
#undef WRITE_SET
#undef COMPUTE

    // ---- epilogue: weighted row-reduction (weights 1-beta^(T-t) on the fly) ----
    // C frag: col = lane&15, row = kblk*4 + r  [verified mapping]
#pragma unroll
    for (int fn = 0; fn < 4; ++fn) {
        const int col = wc * 64 + fn * 16 + arow;
        const float lb = log2f(beta[col]);   // beta in [0,1): log2(0) = -inf -> weight 1
        float s = 0.f;
#pragma unroll
        for (int fm = 0; fm < 2; ++fm) {
#pragma unroll
            for (int r = 0; r < 4; ++r) {
                int t = t0 + wr * 32 + fm * 16 + kblk * 4 + r;
                if (t < T_)
                    s += (1.f - exp2f((float)(T_ - t) * lb)) * acc[fm][fn][r];
            }
        }
        s += __shfl_xor(s, 16);
        s += __shfl_xor(s, 32);
        if (kblk == 0) red[wr][col] = s;   // wc groups write disjoint col ranges
    }
    __syncthreads();

    if (tid < DOUT) {
        float v = red[0][tid] + red[1][tid];
        partials[(((size_t)b * TILES + tile) * NKC + kc) * DOUT + tid] = v;
    }
}

// ---------------- finalize: norm from partials, sum, scale, bias ----------------
__global__ __launch_bounds__(256) void finalize_kernel(
    const float* __restrict__ partials, const float* __restrict__ normPart,
    const float* __restrict__ bias, float* __restrict__ out)
{
    int i = blockIdx.x * 256 + threadIdx.x;  // 8192 = B_*DOUT
    int b = i >> 7, d = i & 127;
    float nrm = 0.f;
#pragma unroll
    for (int g = 0; g < NPREP; ++g)
        nrm += normPart[g * DOUT + d];
    float scale = 1.f / ((nrm + EPSV) * (float)T_);
    float s = 0.f;
#pragma unroll
    for (int p = 0; p < TILES * NKC; ++p)
        s += partials[((size_t)b * TILES * NKC + p) * DOUT + d];
    out[i] = s * scale - bias[d];
}

extern "C" void kernel_launch(void* const* d_in, const int* in_sizes, int n_in,
                              void* d_out, int out_size, void* d_ws, size_t ws_size,
                              hipStream_t stream) {
    const float* x    = (const float*)d_in[0];  // [64][500][1024]
    const float* w    = (const float*)d_in[1];  // [1024][128]
    const float* beta = (const float*)d_in[2];  // [128]
    const float* bias = (const float*)d_in[3];  // [128]
    float* out = (float*)d_out;                 // [64][128] fp32

    char* ws = (char*)d_ws;
    __hip_bfloat16* wT = (__hip_bfloat16*)(ws);
    float* normPart = (float*)(ws + OFF_NORM);
    float* partials = (float*)(ws + OFF_PART);

    prep_kernel<<<NPREP, 512, 0, stream>>>(w, wT, normPart);
    gemm_kernel<<<NGEMM, 256, 0, stream>>>(x, beta, wT, partials);
    finalize_kernel<<<(B_ * DOUT) / 256, 256, 0, stream>>>(partials, normPart, bias, out);
}

// Round 14
// 34.069 us; speedup vs baseline: 1.2088x; 1.2088x over previous
//
#include <hip/hip_runtime.h>
#include <hip/hip_bf16.h>

// Problem constants
#define B_    64
#define T_    500
#define DIN   1024
#define DOUT  128
#define EPSV  1e-8f
#define BM    128          // t-rows per block tile
#define BK    64           // k per LDS stage
#define NKC   2            // k-chunks (exact: weighting is linear in h)
#define KCL   (DIN / NKC)  // 512
#define NKT   (KCL / BK)   // 8 K-steps per block
#define TILES 4            // ceil(500/128)
#define NGEMM (B_ * TILES * NKC)   // 512 blocks = 2/CU
#define NPREP 32

typedef __attribute__((ext_vector_type(8))) short bf16x8;  // MFMA A/B frag
typedef __attribute__((ext_vector_type(4))) float f32x4;   // MFMA C/D frag

// Workspace layout (byte offsets)
//   wT       : bf16 chunked [16][128 cols][64 k]  @ 0        (262144 B)
//   normPart : f32  [NPREP][DOUT]                 @ 262144   (16384 B)
//   part     : f32  [B_][TILES][2][NKC][DOUT]     @ 278528   (524288 B)
#define OFF_NORM  262144
#define OFF_PART  278528

__device__ inline short f2bf(float f) {
    __hip_bfloat16 h = __float2bfloat16(f);
    return __builtin_bit_cast(short, h);
}

// Raw barrier: LDS-drain only; global/DMA ops ride across with counted vmcnt.
__device__ inline void block_sync_lds() {
    asm volatile("s_waitcnt lgkmcnt(0)" ::: "memory");
    __builtin_amdgcn_s_barrier();
    asm volatile("" ::: "memory");
}

// global -> LDS DMA, 16B per lane; LDS dest = wave-uniform base + lane*16
__device__ inline void gload_lds16(const void* g, void* l) {
    __builtin_amdgcn_global_load_lds(
        (const __attribute__((address_space(1))) void*)g,
        (__attribute__((address_space(3))) void*)l, 16, 0, 0);
}

// ---------------- prep: w -> chunked bf16 wT + per-block norm partials ----------------
// wT layout: chunk c = k/64 (16 chunks), within: [col d][64 k] bf16 (128B per col).
// Thread t: d = t&127, kq = t>>7 (8-k group); reads coalesced (64 consecutive-d lanes).
__global__ __launch_bounds__(512) void prep_kernel(
    const float* __restrict__ w, __hip_bfloat16* __restrict__ wT,
    float* __restrict__ normPart)
{
    const int tid = threadIdx.x;
    const int blk = blockIdx.x;
    const int t   = blk * 512 + tid;
    const int d   = t & 127;
    const int kq  = t >> 7;                 // global 8-k group, 0..127
    float v[8];
    float ss = 0.f;
#pragma unroll
    for (int m = 0; m < 8; ++m) {
        v[m] = w[(size_t)(kq * 8 + m) * DOUT + d];
        ss += v[m] * v[m];
    }
    bf16x8 o;
#pragma unroll
    for (int m = 0; m < 8; ++m) o[m] = f2bf(v[m]);
    // chunk = kq>>3, slot = kq&7: off = chunk*8192 + d*64 + slot*8 (elems)
    *reinterpret_cast<bf16x8*>(wT + (size_t)(kq >> 3) * 8192 + d * 64 + (kq & 7) * 8) = o;

    __shared__ float red[512];
    red[tid] = ss;
    __syncthreads();
    if (tid < 128)
        normPart[blk * DOUT + tid] = red[tid] + red[tid + 128] + red[tid + 256] + red[tid + 384];
}

// ---------------- main: R8 core + B via global_load_lds (pre-swizzled source) ----------------
// 512 blocks = 64 b x 4 t-tiles x 2 k-chunks; 512 threads = 8 waves (2 wr x 4 wc).
// LDS double-buffered: A[128][64]bf16 XOR-swizzled (reg-staged, cvt fp32->bf16),
// B[128 cols][64 k]bf16 filled by DMA whose source order bakes in the same swizzle:
// lane l fetches logical slot (l&7)^(l>>3) -> LDS[col][s] = logical[col][s^(col&7)].
// Pipeline: step kt: DMA B(kt+1) -> load A(kt+2) regs -> COMPUTE(kt) -> write A(kt+1)
//           -> vmcnt(8 counted: drains B DMA, keeps A prefetch in flight) -> barrier.
__global__ __launch_bounds__(512, 4) void gemm_kernel(
    const float* __restrict__ x, const float* __restrict__ beta,
    const __hip_bfloat16* __restrict__ wT, float* __restrict__ partials)
{
    __shared__ __align__(16) char smem[2 * 32768];  // per buf: A @0 (16KB), B @16KB

    const int tid  = threadIdx.x;
    const int wid  = tid >> 6;
    const int lane = tid & 63;
    const int wg   = blockIdx.x;
    const int kc   = wg & 1;
    const int tile = (wg >> 1) & 3;
    const int b    = wg >> 3;
    const int t0   = tile * BM;
    const int arow = lane & 15;
    const int kblk = lane >> 4;
    const int wr   = wid >> 2;   // 0..1  (row group of 64)
    const int wc   = wid & 3;    // 0..3  (col group of 32)

    const float* xb = x + (size_t)b * T_ * DIN + kc * KCL;

    // ---- A staging geometry (R8 verbatim) ----
    const int sr = tid >> 4;     // 0..31 (row within pass)
    const int sc = tid & 15;     // float4 index within row
    const float* ag[4];
    int awoff[4];
#pragma unroll
    for (int p = 0; p < 4; ++p) {
        int row  = p * 32 + sr;
        int trow = t0 + row; if (trow >= T_) trow = T_ - 1;  // clamp; weight=0 kills it
        ag[p] = xb + (size_t)trow * DIN + sc * 4;
        awoff[p] = (row * 128 + sc * 8) ^ ((row & 7) << 4);
    }

    // ---- B DMA source geometry: per-lane pre-swizzled offset (elems) ----
    // col = wid*16 + q*8 + (lane>>3); logical slot = (lane&7)^(lane>>3)
    const int boff0 = (wid * 16 + (lane >> 3)) * 64 + (((lane & 7) ^ (lane >> 3)) * 8);
    const __hip_bfloat16* wTb = wT + (size_t)(kc * NKT) * 8192 + boff0;  // + kt*8192 + q*512

    // fragment read offsets, loop-invariant (identical formulas to R8)
    int aro[4][2], bro[2][2];
#pragma unroll
    for (int fm = 0; fm < 4; ++fm)
#pragma unroll
        for (int kk = 0; kk < 2; ++kk) {
            int row = wr * 64 + fm * 16 + arow;
            aro[fm][kk] = (row * 128 + kk * 64 + kblk * 16) ^ ((row & 7) << 4);
        }
#pragma unroll
    for (int fn = 0; fn < 2; ++fn)
#pragma unroll
        for (int kk = 0; kk < 2; ++kk) {
            int col = wc * 32 + fn * 16 + arow;
            bro[fn][kk] = (col * 128 + kk * 64 + kblk * 16) ^ ((col & 7) << 4);
        }

    f32x4 acc[4][2] = {};

#define STAGE_B(KT, BB) { \
    const __hip_bfloat16* s0 = wTb + (size_t)(KT) * 8192; \
    gload_lds16(s0,       (BB) + wid * 2048); \
    gload_lds16(s0 + 512, (BB) + wid * 2048 + 1024); }

#define DECL_SET(S) float4 S##a0, S##a1, S##a2, S##a3;
#define LOAD_A(S, KB) \
    S##a0 = *reinterpret_cast<const float4*>(ag[0] + (KB)); \
    S##a1 = *reinterpret_cast<const float4*>(ag[1] + (KB)); \
    S##a2 = *reinterpret_cast<const float4*>(ag[2] + (KB)); \
    S##a3 = *reinterpret_cast<const float4*>(ag[3] + (KB));
#define WRITE_A(S, AB) { \
    short4 h0; h0.x=f2bf(S##a0.x); h0.y=f2bf(S##a0.y); h0.z=f2bf(S##a0.z); h0.w=f2bf(S##a0.w); \
    *reinterpret_cast<short4*>((AB) + awoff[0]) = h0; \
    short4 h1; h1.x=f2bf(S##a1.x); h1.y=f2bf(S##a1.y); h1.z=f2bf(S##a1.z); h1.w=f2bf(S##a1.w); \
    *reinterpret_cast<short4*>((AB) + awoff[1]) = h1; \
    short4 h2; h2.x=f2bf(S##a2.x); h2.y=f2bf(S##a2.y); h2.z=f2bf(S##a2.z); h2.w=f2bf(S##a2.w); \
    *reinterpret_cast<short4*>((AB) + awoff[2]) = h2; \
    short4 h3; h3.x=f2bf(S##a3.x); h3.y=f2bf(S##a3.y); h3.z=f2bf(S##a3.z); h3.w=f2bf(S##a3.w); \
    *reinterpret_cast<short4*>((AB) + awoff[3]) = h3; }
#define COMPUTE(AB, BB) { \
    _Pragma("unroll") \
    for (int kk = 0; kk < 2; ++kk) { \
        bf16x8 bf0 = *reinterpret_cast<const bf16x8*>((BB) + bro[0][kk]); \
        bf16x8 bf1 = *reinterpret_cast<const bf16x8*>((BB) + bro[1][kk]); \
        _Pragma("unroll") \
        for (int fm = 0; fm < 4; ++fm) { \
            bf16x8 af = *reinterpret_cast<const bf16x8*>((AB) + aro[fm][kk]); \
            acc[fm][0] = __builtin_amdgcn_mfma_f32_16x16x32_bf16(af, bf0, acc[fm][0], 0, 0, 0); \
            acc[fm][1] = __builtin_amdgcn_mfma_f32_16x16x32_bf16(af, bf1, acc[fm][1], 0, 0, 0); \
        } } }
#define VMCNT(N) asm volatile("s_waitcnt vmcnt(" #N ")" ::: "memory");

    DECL_SET(qe_) DECL_SET(qo_)

    // ---- prologue: DMA B(0)->buf0, B(1)->buf1; load A(0),A(1); write A(0) ----
    STAGE_B(0, smem + 16384)
    STAGE_B(1, smem + 32768 + 16384)
    LOAD_A(qe_, 0)
    LOAD_A(qo_, BK)
    WRITE_A(qe_, smem)       // compiler drains A(0) => B(0),B(1) DMAs (older) done too
    VMCNT(8)                 // explicit: only A(1) may remain in flight
    block_sync_lds();

    // ---- main loop, fully unrolled ----
#pragma unroll
    for (int kt = 0; kt < NKT; ++kt) {
        char* Acur = smem + (kt & 1) * 32768;
        char* Bcur = Acur + 16384;
        char* Anxt = smem + ((kt + 1) & 1) * 32768;
        char* Bnxt = Anxt + 16384;

        // B(kt+1) DMA into next buf (region free since barrier at end of kt-1);
        // kt==0's B(1) already staged in prologue.
        if (kt >= 1 && kt + 1 < NKT) { STAGE_B(kt + 1, Bnxt) }
        if (kt + 2 < NKT) {
            if (kt & 1) { LOAD_A(qo_, (kt + 2) * BK) }
            else        { LOAD_A(qe_, (kt + 2) * BK) }
        }

        COMPUTE(Acur, Bcur)

        if (kt + 1 < NKT) {
            if (kt & 1) { WRITE_A(qe_, Anxt) }
            else        { WRITE_A(qo_, Anxt) }
            // counted drain: retire B DMA (oldest), keep A(kt+2) prefetch in flight
            if (kt + 2 < NKT) { VMCNT(8) } else { VMCNT(0) }
            block_sync_lds();
        }
    }
#undef STAGE_B
#undef DECL_SET
#undef LOAD_A
#undef WRITE_A
#undef COMPUTE
#undef VMCNT

    // ---- epilogue (R8 verbatim): weights 1-beta^(T-t) on the fly ----
    // C frag: col = lane&15, row = (lane>>4)*4 + r  [verified mapping]
    const int col0 = wc * 32 + arow;
    const int col1 = col0 + 16;
    const float lb0 = log2f(beta[col0]);   // beta in [0,1): log2(0) = -inf -> weight 1
    const float lb1 = log2f(beta[col1]);
    float s0 = 0.f, s1 = 0.f;
#pragma unroll
    for (int fm = 0; fm < 4; ++fm) {
#pragma unroll
        for (int r = 0; r < 4; ++r) {
            int t = t0 + wr * 64 + fm * 16 + kblk * 4 + r;
            if (t < T_) {
                float e = (float)(T_ - t);
                s0 += (1.f - exp2f(e * lb0)) * acc[fm][0][r];
                s1 += (1.f - exp2f(e * lb1)) * acc[fm][1][r];
            }
        }
    }
    s0 += __shfl_xor(s0, 16); s0 += __shfl_xor(s0, 32);
    s1 += __shfl_xor(s1, 16); s1 += __shfl_xor(s1, 32);

    if (kblk == 0) {
        float* p = partials + ((((size_t)b * TILES + tile) * 2 + wr) * NKC + kc) * DOUT;
        p[col0] = s0;
        p[col1] = s1;
    }
}

// ---------------- finalize: norm from partials, sum, scale, bias ----------------
__global__ __launch_bounds__(256) void finalize_kernel(
    const float* __restrict__ partials, const float* __restrict__ normPart,
    const float* __restrict__ bias, float* __restrict__ out)
{
    int i = blockIdx.x * 256 + threadIdx.x;  // 8192 = B_*DOUT
    int b = i >> 7, d = i & 127;
    float nrm = 0.f;
#pragma unroll
    for (int g = 0; g < NPREP; ++g)
        nrm += normPart[g * DOUT + d];
    float scale = 1.f / ((nrm + EPSV) * (float)T_);
    float s = 0.f;
#pragma unroll
    for (int p = 0; p < TILES * 2 * NKC; ++p)
        s += partials[((size_t)b * TILES * 2 * NKC + p) * DOUT + d];
    out[i] = s * scale - bias[d];
}

extern "C" void kernel_launch(void* const* d_in, const int* in_sizes, int n_in,
                              void* d_out, int out_size, void* d_ws, size_t ws_size,
                              hipStream_t stream) {
    const float* x    = (const float*)d_in[0];  // [64][500][1024]
    const float* w    = (const float*)d_in[1];  // [1024][128]
    const float* beta = (const float*)d_in[2];  // [128]
    const float* bias = (const float*)d_in[3];  // [128]
    float* out = (float*)d_out;                 // [64][128] fp32

    char* ws = (char*)d_ws;
    __hip_bfloat16* wT = (__hip_bfloat16*)(ws);
    float* normPart = (float*)(ws + OFF_NORM);
    float* partials = (float*)(ws + OFF_PART);

    prep_kernel<<<NPREP, 512, 0, stream>>>(w, wT, normPart);
    gemm_kernel<<<NGEMM, 512, 0, stream>>>(x, beta, wT, partials);
    finalize_kernel<<<(B_ * DOUT) / 256, 256, 0, stream>>>(partials, normPart, bias, out);
}

// Round 15
// 33.737 us; speedup vs baseline: 1.2207x; 1.0099x over previous
//
#include <hip/hip_runtime.h>
#include <hip/hip_bf16.h>

// Problem constants
#define B_    64
#define T_    500
#define DIN   1024
#define DOUT  128
#define EPSV  1e-8f
#define BM    128          // t-rows per block tile
#define BK    64           // k per LDS stage
#define NKC   2            // k-chunks (exact: weighting is linear in h)
#define KCL   (DIN / NKC)  // 512
#define NKT   (KCL / BK)   // 8 K-steps per block
#define TILES 4            // ceil(500/128)
#define NGEMM (B_ * TILES * NKC)   // 512 blocks = 2/CU
#define NPREP 32

typedef __attribute__((ext_vector_type(8))) short bf16x8;  // MFMA A/B frag
typedef __attribute__((ext_vector_type(4))) float f32x4;   // MFMA C/D frag

// Workspace layout (byte offsets)
//   wT       : bf16 chunked [16][128 cols][64 k]  @ 0        (262144 B)
//   normPart : f32  [NPREP][DOUT]                 @ 262144   (16384 B)
//   part     : f32  [B_][TILES][2][NKC][DOUT]     @ 278528   (524288 B)
#define OFF_NORM  262144
#define OFF_PART  278528

__device__ inline short f2bf(float f) {
    __hip_bfloat16 h = __float2bfloat16(f);
    return __builtin_bit_cast(short, h);
}

// Raw barrier: LDS-drain only; global/DMA ops ride across with counted vmcnt.
__device__ inline void block_sync_lds() {
    asm volatile("s_waitcnt lgkmcnt(0)" ::: "memory");
    __builtin_amdgcn_s_barrier();
    asm volatile("" ::: "memory");
}

// global -> LDS DMA, 16B per lane; LDS dest = wave-uniform base + lane*16
__device__ inline void gload_lds16(const void* g, void* l) {
    __builtin_amdgcn_global_load_lds(
        (const __attribute__((address_space(1))) void*)g,
        (__attribute__((address_space(3))) void*)l, 16, 0, 0);
}

// ---------------- prep: w -> chunked bf16 wT + per-block norm partials ----------------
// wT layout: chunk c = k/64 (16 chunks), within: [col d][64 k] bf16 (128B per col).
// Thread t: d = t&127, kq = t>>7 (8-k group); reads coalesced (64 consecutive-d lanes).
__global__ __launch_bounds__(512) void prep_kernel(
    const float* __restrict__ w, __hip_bfloat16* __restrict__ wT,
    float* __restrict__ normPart)
{
    const int tid = threadIdx.x;
    const int blk = blockIdx.x;
    const int t   = blk * 512 + tid;
    const int d   = t & 127;
    const int kq  = t >> 7;                 // global 8-k group, 0..127
    float v[8];
    float ss = 0.f;
#pragma unroll
    for (int m = 0; m < 8; ++m) {
        v[m] = w[(size_t)(kq * 8 + m) * DOUT + d];
        ss += v[m] * v[m];
    }
    bf16x8 o;
#pragma unroll
    for (int m = 0; m < 8; ++m) o[m] = f2bf(v[m]);
    // chunk = kq>>3, slot = kq&7: off = chunk*8192 + d*64 + slot*8 (elems)
    *reinterpret_cast<bf16x8*>(wT + (size_t)(kq >> 3) * 8192 + d * 64 + (kq & 7) * 8) = o;

    __shared__ float red[512];
    red[tid] = ss;
    __syncthreads();
    if (tid < 128)
        normPart[blk * DOUT + tid] = red[tid] + red[tid + 128] + red[tid + 256] + red[tid + 384];
}

// ---------------- main: R8 core + B via global_load_lds (pre-swizzled source) ----------------
// 512 blocks = 64 b x 4 t-tiles x 2 k-chunks; 512 threads = 8 waves (2 wr x 4 wc).
// LDS double-buffered: A[128][64]bf16 XOR-swizzled (reg-staged, cvt fp32->bf16),
// B[128 cols][64 k]bf16 filled by DMA whose source order bakes in the same swizzle:
// lane l fetches logical slot (l&7)^(l>>3) -> LDS[col][s] = logical[col][s^(col&7)].
// Pipeline: step kt: DMA B(kt+1) -> load A(kt+2) regs -> COMPUTE(kt) -> write A(kt+1)
//           -> vmcnt(4): retire B(kt+1) DMAs (race fix vs R13's vmcnt(8) no-op),
//              keep the 4 A(kt+2) prefetch loads in flight across the barrier.
__global__ __launch_bounds__(512, 4) void gemm_kernel(
    const float* __restrict__ x, const float* __restrict__ beta,
    const __hip_bfloat16* __restrict__ wT, float* __restrict__ partials)
{
    __shared__ __align__(16) char smem[2 * 32768];  // per buf: A @0 (16KB), B @16KB

    const int tid  = threadIdx.x;
    const int wid  = tid >> 6;
    const int lane = tid & 63;
    const int wg   = blockIdx.x;
    const int kc   = wg & 1;
    const int tile = (wg >> 1) & 3;
    const int b    = wg >> 3;
    const int t0   = tile * BM;
    const int arow = lane & 15;
    const int kblk = lane >> 4;
    const int wr   = wid >> 2;   // 0..1  (row group of 64)
    const int wc   = wid & 3;    // 0..3  (col group of 32)

    const float* xb = x + (size_t)b * T_ * DIN + kc * KCL;

    // ---- A staging geometry (R8 verbatim) ----
    const int sr = tid >> 4;     // 0..31 (row within pass)
    const int sc = tid & 15;     // float4 index within row
    const float* ag[4];
    int awoff[4];
#pragma unroll
    for (int p = 0; p < 4; ++p) {
        int row  = p * 32 + sr;
        int trow = t0 + row; if (trow >= T_) trow = T_ - 1;  // clamp; weight=0 kills it
        ag[p] = xb + (size_t)trow * DIN + sc * 4;
        awoff[p] = (row * 128 + sc * 8) ^ ((row & 7) << 4);
    }

    // ---- B DMA source geometry: per-lane pre-swizzled offset (elems) ----
    // col = wid*16 + q*8 + (lane>>3); logical slot = (lane&7)^(lane>>3)
    const int boff0 = (wid * 16 + (lane >> 3)) * 64 + (((lane & 7) ^ (lane >> 3)) * 8);
    const __hip_bfloat16* wTb = wT + (size_t)(kc * NKT) * 8192 + boff0;  // + kt*8192 + q*512

    // fragment read offsets, loop-invariant (identical formulas to R8)
    int aro[4][2], bro[2][2];
#pragma unroll
    for (int fm = 0; fm < 4; ++fm)
#pragma unroll
        for (int kk = 0; kk < 2; ++kk) {
            int row = wr * 64 + fm * 16 + arow;
            aro[fm][kk] = (row * 128 + kk * 64 + kblk * 16) ^ ((row & 7) << 4);
        }
#pragma unroll
    for (int fn = 0; fn < 2; ++fn)
#pragma unroll
        for (int kk = 0; kk < 2; ++kk) {
            int col = wc * 32 + fn * 16 + arow;
            bro[fn][kk] = (col * 128 + kk * 64 + kblk * 16) ^ ((col & 7) << 4);
        }

    f32x4 acc[4][2] = {};

#define STAGE_B(KT, BB) { \
    const __hip_bfloat16* s0 = wTb + (size_t)(KT) * 8192; \
    gload_lds16(s0,       (BB) + wid * 2048); \
    gload_lds16(s0 + 512, (BB) + wid * 2048 + 1024); }

#define DECL_SET(S) float4 S##a0, S##a1, S##a2, S##a3;
#define LOAD_A(S, KB) \
    S##a0 = *reinterpret_cast<const float4*>(ag[0] + (KB)); \
    S##a1 = *reinterpret_cast<const float4*>(ag[1] + (KB)); \
    S##a2 = *reinterpret_cast<const float4*>(ag[2] + (KB)); \
    S##a3 = *reinterpret_cast<const float4*>(ag[3] + (KB));
#define WRITE_A(S, AB) { \
    short4 h0; h0.x=f2bf(S##a0.x); h0.y=f2bf(S##a0.y); h0.z=f2bf(S##a0.z); h0.w=f2bf(S##a0.w); \
    *reinterpret_cast<short4*>((AB) + awoff[0]) = h0; \
    short4 h1; h1.x=f2bf(S##a1.x); h1.y=f2bf(S##a1.y); h1.z=f2bf(S##a1.z); h1.w=f2bf(S##a1.w); \
    *reinterpret_cast<short4*>((AB) + awoff[1]) = h1; \
    short4 h2; h2.x=f2bf(S##a2.x); h2.y=f2bf(S##a2.y); h2.z=f2bf(S##a2.z); h2.w=f2bf(S##a2.w); \
    *reinterpret_cast<short4*>((AB) + awoff[2]) = h2; \
    short4 h3; h3.x=f2bf(S##a3.x); h3.y=f2bf(S##a3.y); h3.z=f2bf(S##a3.z); h3.w=f2bf(S##a3.w); \
    *reinterpret_cast<short4*>((AB) + awoff[3]) = h3; }
#define COMPUTE(AB, BB) { \
    _Pragma("unroll") \
    for (int kk = 0; kk < 2; ++kk) { \
        bf16x8 bf0 = *reinterpret_cast<const bf16x8*>((BB) + bro[0][kk]); \
        bf16x8 bf1 = *reinterpret_cast<const bf16x8*>((BB) + bro[1][kk]); \
        _Pragma("unroll") \
        for (int fm = 0; fm < 4; ++fm) { \
            bf16x8 af = *reinterpret_cast<const bf16x8*>((AB) + aro[fm][kk]); \
            acc[fm][0] = __builtin_amdgcn_mfma_f32_16x16x32_bf16(af, bf0, acc[fm][0], 0, 0, 0); \
            acc[fm][1] = __builtin_amdgcn_mfma_f32_16x16x32_bf16(af, bf1, acc[fm][1], 0, 0, 0); \
        } } }
#define VMCNT(N) asm volatile("s_waitcnt vmcnt(" #N ")" ::: "memory");

    DECL_SET(qe_) DECL_SET(qo_)

    // ---- prologue: DMA B(0)->buf0, B(1)->buf1; load A(0),A(1); write A(0) ----
    STAGE_B(0, smem + 16384)
    STAGE_B(1, smem + 32768 + 16384)
    LOAD_A(qe_, 0)
    LOAD_A(qo_, BK)
    WRITE_A(qe_, smem)       // A(0) use drains the older B(0)/B(1) DMAs too (in-order retire)
    VMCNT(4)                 // explicit: only A(1)'s 4 loads may remain in flight
    block_sync_lds();

    // ---- main loop, fully unrolled ----
#pragma unroll
    for (int kt = 0; kt < NKT; ++kt) {
        char* Acur = smem + (kt & 1) * 32768;
        char* Bcur = Acur + 16384;
        char* Anxt = smem + ((kt + 1) & 1) * 32768;
        char* Bnxt = Anxt + 16384;

        // B(kt+1) DMA into next buf (region free since barrier at end of kt-1);
        // kt==0's B(1) already staged in prologue.
        if (kt >= 1 && kt + 1 < NKT) { STAGE_B(kt + 1, Bnxt) }
        if (kt + 2 < NKT) {
            if (kt & 1) { LOAD_A(qo_, (kt + 2) * BK) }
            else        { LOAD_A(qe_, (kt + 2) * BK) }
        }

        COMPUTE(Acur, Bcur)

        if (kt + 1 < NKT) {
            if (kt & 1) { WRITE_A(qe_, Anxt) }
            else        { WRITE_A(qo_, Anxt) }
            // counted drain: outstanding here = 2 B DMAs (kt+1) + 4 A loads (kt+2).
            // VMCNT(4) retires the DMAs (B(kt+1) guaranteed in LDS before its ds_read),
            // keeps the A prefetch in flight. Last staged step drains fully.
            if (kt + 2 < NKT) { VMCNT(4) } else { VMCNT(0) }
            block_sync_lds();
        }
    }
#undef STAGE_B
#undef DECL_SET
#undef LOAD_A
#undef WRITE_A
#undef COMPUTE
#undef VMCNT

    // ---- epilogue (R8 verbatim): weights 1-beta^(T-t) on the fly ----
    // C frag: col = lane&15, row = (lane>>4)*4 + r  [verified mapping]
    const int col0 = wc * 32 + arow;
    const int col1 = col0 + 16;
    const float lb0 = log2f(beta[col0]);   // beta in [0,1): log2(0) = -inf -> weight 1
    const float lb1 = log2f(beta[col1]);
    float s0 = 0.f, s1 = 0.f;
#pragma unroll
    for (int fm = 0; fm < 4; ++fm) {
#pragma unroll
        for (int r = 0; r < 4; ++r) {
            int t = t0 + wr * 64 + fm * 16 + kblk * 4 + r;
            if (t < T_) {
                float e = (float)(T_ - t);
                s0 += (1.f - exp2f(e * lb0)) * acc[fm][0][r];
                s1 += (1.f - exp2f(e * lb1)) * acc[fm][1][r];
            }
        }
    }
    s0 += __shfl_xor(s0, 16); s0 += __shfl_xor(s0, 32);
    s1 += __shfl_xor(s1, 16); s1 += __shfl_xor(s1, 32);

    if (kblk == 0) {
        float* p = partials + ((((size_t)b * TILES + tile) * 2 + wr) * NKC + kc) * DOUT;
        p[col0] = s0;
        p[col1] = s1;
    }
}

// ---------------- finalize: norm from partials, sum, scale, bias ----------------
__global__ __launch_bounds__(256) void finalize_kernel(
    const float* __restrict__ partials, const float* __restrict__ normPart,
    const float* __restrict__ bias, float* __restrict__ out)
{
    int i = blockIdx.x * 256 + threadIdx.x;  // 8192 = B_*DOUT
    int b = i >> 7, d = i & 127;
    float nrm = 0.f;
#pragma unroll
    for (int g = 0; g < NPREP; ++g)
        nrm += normPart[g * DOUT + d];
    float scale = 1.f / ((nrm + EPSV) * (float)T_);
    float s = 0.f;
#pragma unroll
    for (int p = 0; p < TILES * 2 * NKC; ++p)
        s += partials[((size_t)b * TILES * 2 * NKC + p) * DOUT + d];
    out[i] = s * scale - bias[d];
}

extern "C" void kernel_launch(void* const* d_in, const int* in_sizes, int n_in,
                              void* d_out, int out_size, void* d_ws, size_t ws_size,
                              hipStream_t stream) {
    const float* x    = (const float*)d_in[0];  // [64][500][1024]
    const float* w    = (const float*)d_in[1];  // [1024][128]
    const float* beta = (const float*)d_in[2];  // [128]
    const float* bias = (const float*)d_in[3];  // [128]
    float* out = (float*)d_out;                 // [64][128] fp32

    char* ws = (char*)d_ws;
    __hip_bfloat16* wT = (__hip_bfloat16*)(ws);
    float* normPart = (float*)(ws + OFF_NORM);
    float* partials = (float*)(ws + OFF_PART);

    prep_kernel<<<NPREP, 512, 0, stream>>>(w, wT, normPart);
    gemm_kernel<<<NGEMM, 512, 0, stream>>>(x, beta, wT, partials);
    finalize_kernel<<<(B_ * DOUT) / 256, 256, 0, stream>>>(partials, normPart, bias, out);
}